// Round 10
// baseline (1223.686 us; speedup 1.0000x reference)
//
#include <hip/hip_runtime.h>
#include <math.h>

// ---------- problem constants ----------
constexpr int SEQ_T = 72;
constexpr int FDIM  = 64;
constexpr int UNITS = 256;
constexpr int U4    = 1024;
constexpr int BATCH = 4096;
constexpr int BM    = 32;          // batch rows per block
constexpr int NKC   = 10;          // k-chunks of 32 (x: kc0-1, h: kc2-9)

// LDS (dynamic):
//   A blob: [2 parities][10 kc][2 m][64 lanes][8 shorts]  -> per-parity A_SH shorts
//   WdL   : [4 ft][8 kcd][64 lanes][8 shorts]
constexpr int A_SH      = NKC * 2 * 64 * 8;                 // 10240 shorts PER PARITY
constexpr int WD_SH     = 4 * 8 * 64 * 8;                   // 16384 shorts
constexpr int LDS_BYTES = (2 * A_SH + WD_SH) * 2;           // 73728 bytes

using bf16x8 = __attribute__((ext_vector_type(8))) short;
using f32x4  = __attribute__((ext_vector_type(4))) float;

__device__ __forceinline__ float sigmoid_fast(float x) {
    return 1.0f / (1.0f + __expf(-x));
}
__device__ __forceinline__ float tanh_fast(float x) {
    float ax = fabsf(x);
    float e  = __expf(2.0f * ax);
    float t  = 1.0f - 2.0f / (e + 1.0f);
    return copysignf(t, x);
}
__device__ __forceinline__ unsigned short f2bf(float f) {
    union { float f; unsigned u; } v; v.f = f;
    unsigned r = (v.u + 0x7FFFu + ((v.u >> 16) & 1u)) >> 16;   // RNE
    return (unsigned short)r;
}

// ---------- prep: z-weights as per-wave MFMA B-fragment blobs ----------
// blob idx = ((w*10 + kc)*4 + ct)*64 + l  (w = wave 0..15 owning units [w*16,w*16+16))
// col = ct*256 + w*16 + (l&15)  (ct = gate) ; k = kc*32 + (l>>4)*8 + e
__global__ void prep_wblob(const float* __restrict__ W, const float* __restrict__ U,
                           unsigned short* __restrict__ Wblob) {
    int id = blockIdx.x * 256 + threadIdx.x;    // 40960
    int l    = id & 63;
    int ct   = (id >> 6) & 3;
    int rest = id >> 8;                          // w*10 + kc
    int kc   = rest % 10, w = rest / 10;
    int col  = ct * 256 + w * 16 + (l & 15);
    int kb   = kc * 32 + (l >> 4) * 8;
    bf16x8 v;
    #pragma unroll
    for (int e = 0; e < 8; ++e) {
        int k = kb + e;
        float f = (k < FDIM) ? W[(size_t)k * U4 + col] : U[(size_t)(k - FDIM) * U4 + col];
        v[e] = (short)f2bf(f);
    }
    *reinterpret_cast<bf16x8*>(Wblob + (size_t)id * 8) = v;
}

// ---------- prep: dense weights as B-fragment blobs ----------
// blob idx = (ft*8 + kcd)*64 + l ; f = ft*16 + (l&15); k = kcd*32 + (l>>4)*8 + e
__global__ void prep_wdblob(const float* __restrict__ Wd, unsigned short* __restrict__ Wdblob) {
    int id = blockIdx.x * 256 + threadIdx.x;    // 2048
    int l   = id & 63;
    int kcd = (id >> 6) & 7;
    int ft  = id >> 9;
    int f   = ft * 16 + (l & 15);
    int kb  = kcd * 32 + (l >> 4) * 8;
    bf16x8 v;
    #pragma unroll
    for (int e = 0; e < 8; ++e)
        v[e] = (short)f2bf(Wd[(size_t)(kb + e) * FDIM + f]);
    *reinterpret_cast<bf16x8*>(Wdblob + (size_t)id * 8) = v;
}

// ---------- persistent, fully block-local LSTM ----------
// grid 128 x 1024 (16 waves, 1 block/CU). Block owns 32 batch rows, ALL 1024 z-cols;
// wave w owns units [w*16,w*16+16) x 4 gates (ct=gate).
// ALL weights streamed per step from L2 (2-deep register pipeline) — nothing
// register-resident across the loop, so the allocator has nothing to sink.
// [x|h] lives in a parity-double-buffered fragment-ordered LDS blob.
__global__ __launch_bounds__(1024, 4) void lstm_persistent(
    const float* __restrict__ inputs,          // [B][72][64] fp32
    const float* __restrict__ bias,            // [1024] fp32
    const unsigned short* __restrict__ Wblob,  // frag-ordered z-weights (640 KB)
    const unsigned short* __restrict__ Wdblob, // frag-ordered dense weights (32 KB)
    const float* __restrict__ bd,              // [64] fp32
    float* __restrict__ out,                   // [B][out_steps][64] fp32
    int out_steps)
{
    extern __shared__ char smem[];
    unsigned short* A_s = (unsigned short*)smem;                    // [2][10][2][64][8]
    unsigned short* WdL = (unsigned short*)(smem + 2 * A_SH * 2);   // [4][8][64][8]

    const int tid  = threadIdx.x;
    const int w    = tid >> 6, lane = tid & 63;
    const int l16  = lane & 15, hi4 = lane >> 4;
    const int bb   = blockIdx.x * BM;

    // ---- Wd blobs -> LDS (2048 x 16B, 2/thread) ----
    #pragma unroll
    for (int i = 0; i < 2; ++i) {
        int bidx = i * 1024 + tid;
        *reinterpret_cast<bf16x8*>(WdL + bidx * 8) =
            *reinterpret_cast<const bf16x8*>(Wdblob + (size_t)bidx * 8);
    }
    // ---- zero h region of A parity 0 (kc2-9, both m): shorts [2048, 10240) ----
    *reinterpret_cast<bf16x8*>(A_s + 2048 + tid * 8) = (bf16x8){0,0,0,0,0,0,0,0};

    float bz[4];
    #pragma unroll
    for (int g = 0; g < 4; ++g) bz[g] = bias[g * 256 + w * 16 + l16];
    const float bdv = (w < 8) ? bd[(w >> 1) * 16 + l16] : 0.0f;

    float c_reg[2][4];
    #pragma unroll
    for (int mt = 0; mt < 2; ++mt)
        #pragma unroll
        for (int j = 0; j < 4; ++j) c_reg[mt][j] = 0.0f;

    // wave's weight-blob base (per-lane)
    const unsigned short* wb = Wblob + ((size_t)(w * 10) * 4 * 64 + lane) * 8;
    const int tmax = SEQ_T + out_steps - 1;    // 95

    #pragma unroll 1
    for (int t = 0; ; ++t) {
        const int p = t & 1;
        unsigned short* Ap = A_s + p * A_SH;

        if (t < SEQ_T) {
            // ---- stage x(t) -> A[p] kc0,1 (coalesced float2/thread) ----
            int r = tid >> 5, c2 = (tid & 31) * 2;
            float2 v = *reinterpret_cast<const float2*>(
                inputs + ((size_t)(bb + r) * SEQ_T + t) * FDIM + c2);
            unsigned lo = f2bf(v.x), hi = f2bf(v.y);
            int kcx = c2 >> 5, m = r >> 4;
            int ls  = (r & 15) | (((c2 >> 3) & 3) << 4);
            *reinterpret_cast<unsigned int*>(
                &Ap[((kcx * 2 + m) * 64 + ls) * 8 + (c2 & 7)]) = lo | (hi << 16);
            __syncthreads();                   // x staged + h-epi(t-1) visible
        } else {
            __syncthreads();                   // B0: h_t visible in A[p]
            // ---- dense head: pred = h @ Wd + bd (waves 0-7: ft=w>>1, mt=w&1) ----
            if (w < 8) {
                const int ft = w >> 1, mt = w & 1;
                f32x4 accp = {0.f, 0.f, 0.f, 0.f};
                #pragma unroll
                for (int kcd = 0; kcd < 8; ++kcd) {
                    bf16x8 a = *reinterpret_cast<const bf16x8*>(
                        &Ap[(((2 + kcd) * 2 + mt) * 64 + lane) * 8]);
                    bf16x8 bfr = *reinterpret_cast<const bf16x8*>(
                        &WdL[((ft * 8 + kcd) * 64 + lane) * 8]);
                    accp = __builtin_amdgcn_mfma_f32_16x16x32_bf16(a, bfr, accp, 0, 0, 0);
                }
                const int s = t - SEQ_T;
                const int f = ft * 16 + l16;
                const int kcx = f >> 5;
                const int lsh = ((f >> 3) & 3) << 4;
                #pragma unroll
                for (int j = 0; j < 4; ++j) {
                    int rr = mt * 16 + hi4 * 4 + j;
                    float v = accp[j] + bdv;
                    out[((size_t)(bb + rr) * out_steps + s) * FDIM + f] = v;
                    Ap[((kcx * 2 + mt) * 64 + ((rr & 15) | lsh)) * 8 + (f & 7)] = f2bf(v);
                }
            }
            if (t == tmax) break;
            __syncthreads();                   // B1: feedback x staged
        }

        // ================ z = [x|h] @ [W;U] : full weight stream ================
        bf16x8 s0[4], s1[4];
        #pragma unroll
        for (int ct = 0; ct < 4; ++ct)
            s0[ct] = *reinterpret_cast<const bf16x8*>(wb + (size_t)(0 * 4 + ct) * 512);
        #pragma unroll
        for (int ct = 0; ct < 4; ++ct)
            s1[ct] = *reinterpret_cast<const bf16x8*>(wb + (size_t)(1 * 4 + ct) * 512);

        f32x4 acc[2][4];
        #pragma unroll
        for (int mt = 0; mt < 2; ++mt)
            #pragma unroll
            for (int g = 0; g < 4; ++g) acc[mt][g] = (f32x4){0.f, 0.f, 0.f, 0.f};

        #pragma unroll
        for (int kc = 0; kc < NKC; ++kc) {
            bf16x8 a0 = *reinterpret_cast<const bf16x8*>(&Ap[((kc * 2 + 0) * 64 + lane) * 8]);
            bf16x8 a1 = *reinterpret_cast<const bf16x8*>(&Ap[((kc * 2 + 1) * 64 + lane) * 8]);
            if ((kc & 1) == 0) {
                #pragma unroll
                for (int ct = 0; ct < 4; ++ct) {
                    acc[0][ct] = __builtin_amdgcn_mfma_f32_16x16x32_bf16(a0, s0[ct], acc[0][ct], 0, 0, 0);
                    acc[1][ct] = __builtin_amdgcn_mfma_f32_16x16x32_bf16(a1, s0[ct], acc[1][ct], 0, 0, 0);
                }
                if (kc + 2 < NKC) {
                    #pragma unroll
                    for (int ct = 0; ct < 4; ++ct)
                        s0[ct] = *reinterpret_cast<const bf16x8*>(
                            wb + (size_t)((kc + 2) * 4 + ct) * 512);
                }
            } else {
                #pragma unroll
                for (int ct = 0; ct < 4; ++ct) {
                    acc[0][ct] = __builtin_amdgcn_mfma_f32_16x16x32_bf16(a0, s1[ct], acc[0][ct], 0, 0, 0);
                    acc[1][ct] = __builtin_amdgcn_mfma_f32_16x16x32_bf16(a1, s1[ct], acc[1][ct], 0, 0, 0);
                }
                if (kc + 2 < NKC) {
                    #pragma unroll
                    for (int ct = 0; ct < 4; ++ct)
                        s1[ct] = *reinterpret_cast<const bf16x8*>(
                            wb + (size_t)((kc + 2) * 4 + ct) * 512);
                }
            }
        }

        // ================ gates + state; h_{t+1} -> A[1-p] kc 2..9 ================
        unsigned short* An = A_s + (1 - p) * A_SH;
        const int kch = 2 + (w >> 1);
        const int lsh = ((w * 2 + (l16 >> 3)) & 3) << 4;
        #pragma unroll
        for (int mt = 0; mt < 2; ++mt) {
            #pragma unroll
            for (int j = 0; j < 4; ++j) {
                float zi = acc[mt][0][j] + bz[0];
                float zf = acc[mt][1][j] + bz[1];
                float zg = acc[mt][2][j] + bz[2];
                float zo = acc[mt][3][j] + bz[3];
                float ig = sigmoid_fast(zi);
                float fg = sigmoid_fast(zf);
                float og = sigmoid_fast(zo);
                float cn = fg * c_reg[mt][j] + ig * tanh_fast(zg);
                c_reg[mt][j] = cn;
                float hv = og * tanh_fast(cn);
                int rl = hi4 * 4 + j;          // row & 15
                An[((kch * 2 + mt) * 64 + (rl | lsh)) * 8 + (l16 & 7)] = f2bf(hv);
            }
        }
    }
}

extern "C" void kernel_launch(void* const* d_in, const int* in_sizes, int n_in,
                              void* d_out, int out_size, void* d_ws, size_t ws_size,
                              hipStream_t stream) {
    const float* inputs = (const float*)d_in[0];
    const float* W      = (const float*)d_in[1];
    const float* U      = (const float*)d_in[2];
    const float* b      = (const float*)d_in[3];
    const float* Wd     = (const float*)d_in[4];
    const float* bd     = (const float*)d_in[5];
    float* out = (float*)d_out;

    const int out_steps = out_size / (BATCH * FDIM);   // 24

    char* ws = (char*)d_ws;
    unsigned short* Wblob  = (unsigned short*)(ws);               // 640 KB
    unsigned short* Wdblob = (unsigned short*)(ws + (1u << 20));  // 32 KB

    prep_wblob<<<160, 256, 0, stream>>>(W, U, Wblob);
    prep_wdblob<<<8, 256, 0, stream>>>(Wd, Wdblob);

    (void)hipFuncSetAttribute((const void*)lstm_persistent,
                              hipFuncAttributeMaxDynamicSharedMemorySize, LDS_BYTES);

    lstm_persistent<<<dim3(BATCH / BM), dim3(1024), LDS_BYTES, stream>>>(
        inputs, b, Wblob, Wdblob, bd, out, out_steps);
}